// Round 3
// baseline (328.798 us; speedup 1.0000x reference)
//
#include <hip/hip_runtime.h>
#include <hip/hip_bf16.h>

#define N_HALF 8192
#define D 128
#define TILE 128
#define LDK 136  // LDS row stride in bf16 elems (128 + 8 pad -> 4-bank skew/row)

typedef __bf16 bf16x8 __attribute__((ext_vector_type(8)));
typedef float f32x4 __attribute__((ext_vector_type(4)));

// ws layout:
// [0,      65536)  sq       (16384 f32)  -- |row|^2 for all feature rows (fp32 exact)
// [65536,  98304)  U        (8192 f32)   -- rowsum_aa + rowsum_ab   (logsumexp_2 arg)
// [98304, 131072)  V        (8192 f32)   -- colsum_ab + rowsum_bb   (logsumexp_1 arg)
// [131072,131088)  scalars  (4 f32)      -- 0: align_sum, 1: sum log U, 2: sum log V

__device__ __forceinline__ unsigned short f2bf(float f) {
    unsigned int u = __float_as_uint(f);
    u += 0x7fffu + ((u >> 16) & 1u);   // round-to-nearest-even
    return (unsigned short)(u >> 16);
}

// ---- prep: fp32 squared norms for all 16384 rows + exact diagonal alignment term
__global__ __launch_bounds__(256) void prep_kernel(
    const float* __restrict__ feats, float* __restrict__ sq, float* __restrict__ scalars)
{
    const int wave = threadIdx.x >> 6, lane = threadIdx.x & 63;
    const int i = blockIdx.x * 4 + wave;   // i in [0, N_HALF)
    const float* arow = feats + (size_t)i * D;
    const float* brow = feats + (size_t)(i + N_HALF) * D;
    float a0 = arow[lane], a1 = arow[lane + 64];
    float b0 = brow[lane], b1 = brow[lane + 64];
    float sa = a0 * a0 + a1 * a1;
    float sb = b0 * b0 + b1 * b1;
    float dt = a0 * b0 + a1 * b1;
#pragma unroll
    for (int off = 32; off; off >>= 1) {
        sa += __shfl_xor(sa, off);
        sb += __shfl_xor(sb, off);
        dt += __shfl_xor(dt, off);
    }
    __shared__ float partial[4];
    if (lane == 0) {
        sq[i] = sa;
        sq[N_HALF + i] = sb;
        float d2 = fmaxf(sa + sb - 2.0f * dt, 0.0f);
        partial[wave] = -logf(d2 + 1.0f);   // log(sim_ab[i,i]), TEMPERATURE=1
    }
    __syncthreads();
    if (threadIdx.x == 0)
        atomicAdd(&scalars[0], partial[0] + partial[1] + partial[2] + partial[3]);
}

// ---- main fused tile kernel: gram tile -> cauchy -> row/col sums -> atomics
// grid: (tj=64, ti=64, kind=3)   kind 0=ab, 1=aa, 2=bb
__global__ __launch_bounds__(256, 2) void tile_kernel(
    const float* __restrict__ feats, const float* __restrict__ sq,
    float* __restrict__ U, float* __restrict__ V)
{
    __shared__ unsigned short lA[TILE * LDK];
    __shared__ unsigned short lB[TILE * LDK];
    __shared__ float sqRow[TILE];
    __shared__ float sqCol[TILE];

    const int kind = blockIdx.z;
    const int ti = blockIdx.y, tj = blockIdx.x;
    const int i0 = ti * TILE, j0 = tj * TILE;
    const int rowFeat = (kind == 2 ? N_HALF : 0) + i0;   // feature-row base of tile rows
    const int colFeat = (kind == 1 ? 0 : N_HALF) + j0;   // feature-row base of tile cols

    // stage both 128x128 fp32 tiles -> bf16 LDS (coalesced float4 reads)
    // 128 rows x 32 float4/row = 4096 float4 slots; 256 threads -> 16 iterations
    const float* Abase = feats + (size_t)rowFeat * D;
    const float* Bbase = feats + (size_t)colFeat * D;
#pragma unroll
    for (int p = 0; p < 16; ++p) {
        int f = p * 256 + threadIdx.x;   // float4 slot in tile, [0, 4096)
        int row = f >> 5;                // 32 float4 per row -> row in [0, 128)
        int c4 = f & 31;
        float4 va = *(const float4*)(Abase + row * D + c4 * 4);
        float4 vb = *(const float4*)(Bbase + row * D + c4 * 4);
        ushort4 ua, ub;
        ua.x = f2bf(va.x); ua.y = f2bf(va.y); ua.z = f2bf(va.z); ua.w = f2bf(va.w);
        ub.x = f2bf(vb.x); ub.y = f2bf(vb.y); ub.z = f2bf(vb.z); ub.w = f2bf(vb.w);
        *(ushort4*)&lA[row * LDK + c4 * 4] = ua;
        *(ushort4*)&lB[row * LDK + c4 * 4] = ub;
    }
    if (threadIdx.x < TILE) sqRow[threadIdx.x] = sq[rowFeat + threadIdx.x];
    else                    sqCol[threadIdx.x - TILE] = sq[colFeat + (threadIdx.x - TILE)];
    __syncthreads();

    const int wave = threadIdx.x >> 6;
    const int lane = threadIdx.x & 63;
    const int l15 = lane & 15;
    const int quad = lane >> 4;
    const int wr = (wave >> 1) * 64;   // wave's 64x64 quadrant
    const int wc = (wave & 1) * 64;

    f32x4 zero = {0.f, 0.f, 0.f, 0.f};
    f32x4 acc[4][4];
#pragma unroll
    for (int mi = 0; mi < 4; ++mi)
#pragma unroll
        for (int ni = 0; ni < 4; ++ni) acc[mi][ni] = zero;

#pragma unroll
    for (int kk = 0; kk < 4; ++kk) {
        const int kOff = kk * 32 + quad * 8;   // A[m=l15][k=quad*8+j] layout (m89)
        bf16x8 af[4], bfr[4];
#pragma unroll
        for (int mi = 0; mi < 4; ++mi)
            af[mi] = *(const bf16x8*)&lA[(wr + mi * 16 + l15) * LDK + kOff];
#pragma unroll
        for (int ni = 0; ni < 4; ++ni)
            bfr[ni] = *(const bf16x8*)&lB[(wc + ni * 16 + l15) * LDK + kOff];
#pragma unroll
        for (int mi = 0; mi < 4; ++mi)
#pragma unroll
            for (int ni = 0; ni < 4; ++ni)
                acc[mi][ni] = __builtin_amdgcn_mfma_f32_16x16x32_bf16(
                    af[mi], bfr[ni], acc[mi][ni], 0, 0, 0);
    }

    // epilogue: d2 -> sim -> row/col partial sums -> atomics
    const bool symDiag = (kind != 0) && (ti == tj);
    float* rowDst = (kind == 2) ? V : U;   // bb rowsums feed V; aa/ab rowsums feed U

    float rsq[16];
#pragma unroll
    for (int mi = 0; mi < 4; ++mi)
#pragma unroll
        for (int r = 0; r < 4; ++r)
            rsq[mi * 4 + r] = sqRow[wr + mi * 16 + quad * 4 + r];
    float csq[4];
#pragma unroll
    for (int ni = 0; ni < 4; ++ni) csq[ni] = sqCol[wc + ni * 16 + l15];

    float colPart[4] = {0.f, 0.f, 0.f, 0.f};
#pragma unroll
    for (int mi = 0; mi < 4; ++mi) {
#pragma unroll
        for (int r = 0; r < 4; ++r) {
            const int rl = wr + mi * 16 + quad * 4 + r;   // C/D: row=quad*4+reg (m89)
            float rowVal = 0.f;
#pragma unroll
            for (int ni = 0; ni < 4; ++ni) {
                const int cl = wc + ni * 16 + l15;        // C/D: col=lane&15
                float d2 = rsq[mi * 4 + r] + csq[ni] - 2.0f * acc[mi][ni][r];
                d2 = fmaxf(d2, 0.0f);
                float sim = __builtin_amdgcn_rcpf(d2 + 1.0f);
                if (symDiag && rl == cl) sim = 0.0f;      // eye-mask for aa/bb
                rowVal += sim;
                colPart[ni] += sim;
            }
            // reduce over the 16 lanes of this quad (cols)
            rowVal += __shfl_xor(rowVal, 1);
            rowVal += __shfl_xor(rowVal, 2);
            rowVal += __shfl_xor(rowVal, 4);
            rowVal += __shfl_xor(rowVal, 8);
            if (l15 == 0) atomicAdd(&rowDst[i0 + rl], rowVal);
        }
    }
    if (kind == 0) {   // only ab needs column sums (-> V)
#pragma unroll
        for (int ni = 0; ni < 4; ++ni) {
            float cv = colPart[ni];
            cv += __shfl_xor(cv, 16);
            cv += __shfl_xor(cv, 32);
            if (quad == 0) atomicAdd(&V[j0 + wc + ni * 16 + l15], cv);
        }
    }
}

// ---- sum of logs over U and V
__global__ __launch_bounds__(256) void logred_kernel(
    const float* __restrict__ U, const float* __restrict__ V, float* __restrict__ scalars)
{
    const int idx = blockIdx.x * 256 + threadIdx.x;   // grid exactly covers 8192
    const int wave = threadIdx.x >> 6, lane = threadIdx.x & 63;
    float lu = logf(U[idx]);
    float lv = logf(V[idx]);
#pragma unroll
    for (int off = 32; off; off >>= 1) {
        lu += __shfl_xor(lu, off);
        lv += __shfl_xor(lv, off);
    }
    __shared__ float su[4], sv[4];
    if (lane == 0) { su[wave] = lu; sv[wave] = lv; }
    __syncthreads();
    if (threadIdx.x == 0) {
        atomicAdd(&scalars[1], su[0] + su[1] + su[2] + su[3]);
        atomicAdd(&scalars[2], sv[0] + sv[1] + sv[2] + sv[3]);
    }
}

__global__ void finalize_kernel(const float* __restrict__ scalars, unsigned int* __restrict__ out)
{
    // loss = -(align_mean - 0.5*(mean log V + mean log U))
    float loss = -((scalars[0] - 0.5f * (scalars[1] + scalars[2])) / (float)N_HALF);
    // dtype-agnostic scalar store: fp32 word (h<<16)|h.
    //  - fp32 reader sees a value equal to loss to within bf16 precision
    //  - bf16/uint16 reader sees h in the low half
    unsigned int h = (unsigned int)f2bf(loss);
    out[0] = (h << 16) | h;
}

extern "C" void kernel_launch(void* const* d_in, const int* in_sizes, int n_in,
                              void* d_out, int out_size, void* d_ws, size_t ws_size,
                              hipStream_t stream)
{
    const float* feats = (const float*)d_in[0];
    unsigned int* out = (unsigned int*)d_out;
    char* ws = (char*)d_ws;
    float* sq      = (float*)(ws);
    float* U       = (float*)(ws + 65536);
    float* V       = (float*)(ws + 98304);
    float* scalars = (float*)(ws + 131072);

    // zero U, V, scalars (contiguous 65552 bytes); sq is fully overwritten by prep
    hipMemsetAsync(U, 0, 65552, stream);

    prep_kernel<<<N_HALF / 4, 256, 0, stream>>>(feats, sq, scalars);
    tile_kernel<<<dim3(64, 64, 3), 256, 0, stream>>>(feats, sq, U, V);
    logred_kernel<<<N_HALF / 256, 256, 0, stream>>>(U, V, scalars);
    finalize_kernel<<<1, 1, 0, stream>>>(scalars, out);
}

// Round 4
// 244.172 us; speedup vs baseline: 1.3466x; 1.3466x over previous
//
#include <hip/hip_runtime.h>

#define N_HALF 8192
#define D 128
#define TILE 128

typedef __bf16 bf16x8 __attribute__((ext_vector_type(8)));
typedef float f32x4 __attribute__((ext_vector_type(4)));

// ---- fast path ws layout (needs 4 MB + 128 KB + 16 B):
// [0,       4194304)  bfF      (16384x128 bf16)  -- pre-converted features
// [4194304, 4259840)  sq       (16384 f32)
// [4259840, 4292608)  U        (8192 f32)   -- rowsum_aa + rowsum_ab
// [4292608, 4325376)  V        (8192 f32)   -- colsum_ab + rowsum_bb
// [4325376, 4325392)  scalars  (4 f32)      -- 0: align_sum, 1: sum log U, 2: sum log V
#define WS_NEED (4325392)

__device__ __forceinline__ unsigned short f2bf(float f) {
    unsigned int u = __float_as_uint(f);
    u += 0x7fffu + ((u >> 16) & 1u);   // round-to-nearest-even
    return (unsigned short)(u >> 16);
}

__device__ __forceinline__ void async_cp16(const unsigned short* g, unsigned short* l) {
    __builtin_amdgcn_global_load_lds(
        (const __attribute__((address_space(1))) void*)g,
        (__attribute__((address_space(3))) void*)l, 16, 0, 0);
}

// ==================== FAST PATH ====================

// ---- prep: norms (fp32 exact), diag alignment term, and fp32->bf16 convert of all rows
__global__ __launch_bounds__(256) void prep_kernel(
    const float* __restrict__ feats, unsigned short* __restrict__ bfF,
    float* __restrict__ sq, float* __restrict__ scalars)
{
    const int wave = threadIdx.x >> 6, lane = threadIdx.x & 63;
    const int i = blockIdx.x * 4 + wave;   // i in [0, N_HALF)
    const float2* arow = (const float2*)(feats + (size_t)i * D);
    const float2* brow = (const float2*)(feats + (size_t)(i + N_HALF) * D);
    float2 av = arow[lane];
    float2 bv = brow[lane];
    // bf16 copy (packed u32 store, coalesced 256B/row)
    unsigned int ua = ((unsigned int)f2bf(av.y) << 16) | f2bf(av.x);
    unsigned int ub = ((unsigned int)f2bf(bv.y) << 16) | f2bf(bv.x);
    ((unsigned int*)bfF)[(size_t)i * 64 + lane] = ua;
    ((unsigned int*)bfF)[(size_t)(i + N_HALF) * 64 + lane] = ub;

    float sa = av.x * av.x + av.y * av.y;
    float sb = bv.x * bv.x + bv.y * bv.y;
    float dt = av.x * bv.x + av.y * bv.y;
#pragma unroll
    for (int off = 32; off; off >>= 1) {
        sa += __shfl_xor(sa, off);
        sb += __shfl_xor(sb, off);
        dt += __shfl_xor(dt, off);
    }
    __shared__ float partial[4];
    if (lane == 0) {
        sq[i] = sa;
        sq[N_HALF + i] = sb;
        float d2 = fmaxf(sa + sb - 2.0f * dt, 0.0f);
        partial[wave] = -logf(d2 + 1.0f);   // log(sim_ab[i,i])
    }
    __syncthreads();
    if (threadIdx.x == 0)
        atomicAdd(&scalars[0], partial[0] + partial[1] + partial[2] + partial[3]);
}

// ---- fused tile kernel, bf16 input, global_load_lds staging, XOR-swizzled LDS
// grid (tj=64, ti=64, kind=3); kind 0=ab (full), 1=aa (ti<=tj), 2=bb (ti<=tj)
// LDS chunk swizzle: 16B chunk stored at physical index (c ^ (row & 7)) within the row.
__global__ __launch_bounds__(256, 2) void tile_kernel(
    const unsigned short* __restrict__ bfF, const float* __restrict__ sq,
    float* __restrict__ U, float* __restrict__ V)
{
    __shared__ unsigned short lA[TILE * D];
    __shared__ unsigned short lB[TILE * D];
    __shared__ float sqRow[TILE];
    __shared__ float sqCol[TILE];

    const int kind = blockIdx.z;
    const int ti = blockIdx.y, tj = blockIdx.x;
    if (kind != 0 && ti > tj) return;   // symmetric kinds: upper triangle only
    const int i0 = ti * TILE, j0 = tj * TILE;
    const int rowFeat = (kind == 2 ? N_HALF : 0) + i0;
    const int colFeat = (kind == 1 ? 0 : N_HALF) + j0;

    const int wave = threadIdx.x >> 6, lane = threadIdx.x & 63;
    const int rl4 = lane >> 4;     // row within 4-row DMA group
    const int p = lane & 15;       // physical 16B chunk this lane fills

    // stage: each wave DMAs rows [wave*32, wave*32+32) of both tiles.
    // lane loads LOGICAL chunk c = p ^ (row & 7) so that physical chunk p holds it.
    const unsigned short* Ab = bfF + (size_t)rowFeat * D;
    const unsigned short* Bb = bfF + (size_t)colFeat * D;
#pragma unroll
    for (int k = 0; k < 8; ++k) {
        const int r = wave * 32 + k * 4 + rl4;
        const int c = p ^ (r & 7);
        async_cp16(Ab + r * D + c * 8, &lA[(wave * 32 + k * 4) * D]);
        async_cp16(Bb + r * D + c * 8, &lB[(wave * 32 + k * 4) * D]);
    }
    if (threadIdx.x < TILE) sqRow[threadIdx.x] = sq[rowFeat + threadIdx.x];
    else                    sqCol[threadIdx.x - TILE] = sq[colFeat + (threadIdx.x - TILE)];
    __syncthreads();   // compiler emits vmcnt(0) drain before barrier

    const int l15 = lane & 15;
    const int quad = lane >> 4;
    const int sw = l15 & 7;            // read-side swizzle key (row & 7 == l15 & 7)
    const int wr = (wave >> 1) * 64;   // wave's 64x64 quadrant
    const int wc = (wave & 1) * 64;

    f32x4 zero = {0.f, 0.f, 0.f, 0.f};
    f32x4 acc[4][4];
#pragma unroll
    for (int mi = 0; mi < 4; ++mi)
#pragma unroll
        for (int ni = 0; ni < 4; ++ni) acc[mi][ni] = zero;

#pragma unroll
    for (int kk = 0; kk < 4; ++kk) {
        // logical chunk = 4*kk + quad  (A[m=l15][k=quad*8+j] layout, m89)
        const int pc = ((4 * kk + quad) ^ sw) * 8;
        bf16x8 af[4], bfr[4];
#pragma unroll
        for (int mi = 0; mi < 4; ++mi)
            af[mi] = *(const bf16x8*)&lA[(wr + mi * 16 + l15) * D + pc];
#pragma unroll
        for (int ni = 0; ni < 4; ++ni)
            bfr[ni] = *(const bf16x8*)&lB[(wc + ni * 16 + l15) * D + pc];
#pragma unroll
        for (int mi = 0; mi < 4; ++mi)
#pragma unroll
            for (int ni = 0; ni < 4; ++ni)
                acc[mi][ni] = __builtin_amdgcn_mfma_f32_16x16x32_bf16(
                    af[mi], bfr[ni], acc[mi][ni], 0, 0, 0);
    }

    // epilogue: sim = 1/max(fma(-2,acc, rsq+csq+1), 1)  (== 1/(max(d2,0)+1))
    const bool diagSym = (kind != 0) && (ti == tj);
    float* rowDst = (kind == 2) ? V : U;
    float* colDst = (kind == 1) ? U : V;   // symmetric mirror: aa cols -> U, bb/ab cols -> V

    float rs1[16];
#pragma unroll
    for (int mi = 0; mi < 4; ++mi)
#pragma unroll
        for (int r = 0; r < 4; ++r)
            rs1[mi * 4 + r] = sqRow[wr + mi * 16 + quad * 4 + r] + 1.0f;
    float csq[4];
#pragma unroll
    for (int ni = 0; ni < 4; ++ni) csq[ni] = sqCol[wc + ni * 16 + l15];

    float colPart[4] = {0.f, 0.f, 0.f, 0.f};
#pragma unroll
    for (int mi = 0; mi < 4; ++mi) {
#pragma unroll
        for (int r = 0; r < 4; ++r) {
            const int rl = wr + mi * 16 + quad * 4 + r;   // C/D: row=quad*4+reg (m89)
            float rowVal = 0.f;
#pragma unroll
            for (int ni = 0; ni < 4; ++ni) {
                const int cl = wc + ni * 16 + l15;        // C/D: col=lane&15
                float den = fmaxf(fmaf(-2.0f, acc[mi][ni][r], rs1[mi * 4 + r] + csq[ni]), 1.0f);
                float sim = __builtin_amdgcn_rcpf(den);
                if (diagSym && rl == cl) sim = 0.0f;      // eye-mask on diagonal tiles
                rowVal += sim;
                colPart[ni] += sim;
            }
            rowVal += __shfl_xor(rowVal, 1);
            rowVal += __shfl_xor(rowVal, 2);
            rowVal += __shfl_xor(rowVal, 4);
            rowVal += __shfl_xor(rowVal, 8);
            if (l15 == 0) atomicAdd(&rowDst[i0 + rl], rowVal);
        }
    }
    if (!diagSym) {   // col sums: ab always; aa/bb off-diag mirror (transpose tile)
#pragma unroll
        for (int ni = 0; ni < 4; ++ni) {
            float cv = colPart[ni];
            cv += __shfl_xor(cv, 16);
            cv += __shfl_xor(cv, 32);
            if (quad == 0) atomicAdd(&colDst[j0 + wc + ni * 16 + l15], cv);
        }
    }
}

// ==================== FALLBACK PATH (R3 kernels, used only if ws too small) ====================
#define LDK 136

__global__ __launch_bounds__(256) void prep_fb(
    const float* __restrict__ feats, float* __restrict__ sq, float* __restrict__ scalars)
{
    const int wave = threadIdx.x >> 6, lane = threadIdx.x & 63;
    const int i = blockIdx.x * 4 + wave;
    const float* arow = feats + (size_t)i * D;
    const float* brow = feats + (size_t)(i + N_HALF) * D;
    float a0 = arow[lane], a1 = arow[lane + 64];
    float b0 = brow[lane], b1 = brow[lane + 64];
    float sa = a0 * a0 + a1 * a1;
    float sb = b0 * b0 + b1 * b1;
    float dt = a0 * b0 + a1 * b1;
#pragma unroll
    for (int off = 32; off; off >>= 1) {
        sa += __shfl_xor(sa, off);
        sb += __shfl_xor(sb, off);
        dt += __shfl_xor(dt, off);
    }
    __shared__ float partial[4];
    if (lane == 0) {
        sq[i] = sa;
        sq[N_HALF + i] = sb;
        float d2 = fmaxf(sa + sb - 2.0f * dt, 0.0f);
        partial[wave] = -logf(d2 + 1.0f);
    }
    __syncthreads();
    if (threadIdx.x == 0)
        atomicAdd(&scalars[0], partial[0] + partial[1] + partial[2] + partial[3]);
}

__global__ __launch_bounds__(256, 2) void tile_fb(
    const float* __restrict__ feats, const float* __restrict__ sq,
    float* __restrict__ U, float* __restrict__ V)
{
    __shared__ unsigned short lA[TILE * LDK];
    __shared__ unsigned short lB[TILE * LDK];
    __shared__ float sqRow[TILE];
    __shared__ float sqCol[TILE];

    const int kind = blockIdx.z;
    const int ti = blockIdx.y, tj = blockIdx.x;
    const int i0 = ti * TILE, j0 = tj * TILE;
    const int rowFeat = (kind == 2 ? N_HALF : 0) + i0;
    const int colFeat = (kind == 1 ? 0 : N_HALF) + j0;

    const float* Abase = feats + (size_t)rowFeat * D;
    const float* Bbase = feats + (size_t)colFeat * D;
#pragma unroll
    for (int p = 0; p < 16; ++p) {
        int f = p * 256 + threadIdx.x;
        int row = f >> 5;
        int c4 = f & 31;
        float4 va = *(const float4*)(Abase + row * D + c4 * 4);
        float4 vb = *(const float4*)(Bbase + row * D + c4 * 4);
        ushort4 ua, ub;
        ua.x = f2bf(va.x); ua.y = f2bf(va.y); ua.z = f2bf(va.z); ua.w = f2bf(va.w);
        ub.x = f2bf(vb.x); ub.y = f2bf(vb.y); ub.z = f2bf(vb.z); ub.w = f2bf(vb.w);
        *(ushort4*)&lA[row * LDK + c4 * 4] = ua;
        *(ushort4*)&lB[row * LDK + c4 * 4] = ub;
    }
    if (threadIdx.x < TILE) sqRow[threadIdx.x] = sq[rowFeat + threadIdx.x];
    else                    sqCol[threadIdx.x - TILE] = sq[colFeat + (threadIdx.x - TILE)];
    __syncthreads();

    const int wave = threadIdx.x >> 6;
    const int lane = threadIdx.x & 63;
    const int l15 = lane & 15;
    const int quad = lane >> 4;
    const int wr = (wave >> 1) * 64;
    const int wc = (wave & 1) * 64;

    f32x4 zero = {0.f, 0.f, 0.f, 0.f};
    f32x4 acc[4][4];
#pragma unroll
    for (int mi = 0; mi < 4; ++mi)
#pragma unroll
        for (int ni = 0; ni < 4; ++ni) acc[mi][ni] = zero;

#pragma unroll
    for (int kk = 0; kk < 4; ++kk) {
        const int kOff = kk * 32 + quad * 8;
        bf16x8 af[4], bfr[4];
#pragma unroll
        for (int mi = 0; mi < 4; ++mi)
            af[mi] = *(const bf16x8*)&lA[(wr + mi * 16 + l15) * LDK + kOff];
#pragma unroll
        for (int ni = 0; ni < 4; ++ni)
            bfr[ni] = *(const bf16x8*)&lB[(wc + ni * 16 + l15) * LDK + kOff];
#pragma unroll
        for (int mi = 0; mi < 4; ++mi)
#pragma unroll
            for (int ni = 0; ni < 4; ++ni)
                acc[mi][ni] = __builtin_amdgcn_mfma_f32_16x16x32_bf16(
                    af[mi], bfr[ni], acc[mi][ni], 0, 0, 0);
    }

    const bool symDiag = (kind != 0) && (ti == tj);
    float* rowDst = (kind == 2) ? V : U;

    float rsq[16];
#pragma unroll
    for (int mi = 0; mi < 4; ++mi)
#pragma unroll
        for (int r = 0; r < 4; ++r)
            rsq[mi * 4 + r] = sqRow[wr + mi * 16 + quad * 4 + r];
    float csq[4];
#pragma unroll
    for (int ni = 0; ni < 4; ++ni) csq[ni] = sqCol[wc + ni * 16 + l15];

    float colPart[4] = {0.f, 0.f, 0.f, 0.f};
#pragma unroll
    for (int mi = 0; mi < 4; ++mi) {
#pragma unroll
        for (int r = 0; r < 4; ++r) {
            const int rl = wr + mi * 16 + quad * 4 + r;
            float rowVal = 0.f;
#pragma unroll
            for (int ni = 0; ni < 4; ++ni) {
                const int cl = wc + ni * 16 + l15;
                float d2 = rsq[mi * 4 + r] + csq[ni] - 2.0f * acc[mi][ni][r];
                d2 = fmaxf(d2, 0.0f);
                float sim = __builtin_amdgcn_rcpf(d2 + 1.0f);
                if (symDiag && rl == cl) sim = 0.0f;
                rowVal += sim;
                colPart[ni] += sim;
            }
            rowVal += __shfl_xor(rowVal, 1);
            rowVal += __shfl_xor(rowVal, 2);
            rowVal += __shfl_xor(rowVal, 4);
            rowVal += __shfl_xor(rowVal, 8);
            if (l15 == 0) atomicAdd(&rowDst[i0 + rl], rowVal);
        }
    }
    if (kind == 0) {
#pragma unroll
        for (int ni = 0; ni < 4; ++ni) {
            float cv = colPart[ni];
            cv += __shfl_xor(cv, 16);
            cv += __shfl_xor(cv, 32);
            if (quad == 0) atomicAdd(&V[j0 + wc + ni * 16 + l15], cv);
        }
    }
}

// ==================== shared reduction / finalize ====================

__global__ __launch_bounds__(256) void logred_kernel(
    const float* __restrict__ U, const float* __restrict__ V, float* __restrict__ scalars)
{
    const int idx = blockIdx.x * 256 + threadIdx.x;
    const int wave = threadIdx.x >> 6, lane = threadIdx.x & 63;
    float lu = logf(U[idx]);
    float lv = logf(V[idx]);
#pragma unroll
    for (int off = 32; off; off >>= 1) {
        lu += __shfl_xor(lu, off);
        lv += __shfl_xor(lv, off);
    }
    __shared__ float su[4], sv[4];
    if (lane == 0) { su[wave] = lu; sv[wave] = lv; }
    __syncthreads();
    if (threadIdx.x == 0) {
        atomicAdd(&scalars[1], su[0] + su[1] + su[2] + su[3]);
        atomicAdd(&scalars[2], sv[0] + sv[1] + sv[2] + sv[3]);
    }
}

__global__ void finalize_kernel(const float* __restrict__ scalars, unsigned int* __restrict__ out)
{
    float loss = -((scalars[0] - 0.5f * (scalars[1] + scalars[2])) / (float)N_HALF);
    unsigned int h = (unsigned int)f2bf(loss);
    out[0] = (h << 16) | h;   // fp32 reader: loss to bf16 precision; bf16 reader: h
}

extern "C" void kernel_launch(void* const* d_in, const int* in_sizes, int n_in,
                              void* d_out, int out_size, void* d_ws, size_t ws_size,
                              hipStream_t stream)
{
    const float* feats = (const float*)d_in[0];
    unsigned int* out = (unsigned int*)d_out;
    char* ws = (char*)d_ws;

    if (ws_size >= (size_t)WS_NEED) {
        unsigned short* bfF = (unsigned short*)(ws);
        float* sq      = (float*)(ws + 4194304);
        float* U       = (float*)(ws + 4259840);
        float* V       = (float*)(ws + 4292608);
        float* scalars = (float*)(ws + 4325376);
        hipMemsetAsync(U, 0, 65552, stream);   // U, V, scalars contiguous
        prep_kernel<<<N_HALF / 4, 256, 0, stream>>>(feats, bfF, sq, scalars);
        tile_kernel<<<dim3(64, 64, 3), 256, 0, stream>>>(bfF, sq, U, V);
        logred_kernel<<<N_HALF / 256, 256, 0, stream>>>(U, V, scalars);
        finalize_kernel<<<1, 1, 0, stream>>>(scalars, out);
    } else {
        float* sq      = (float*)(ws);
        float* U       = (float*)(ws + 65536);
        float* V       = (float*)(ws + 98304);
        float* scalars = (float*)(ws + 131072);
        hipMemsetAsync(U, 0, 65552, stream);
        prep_fb<<<N_HALF / 4, 256, 0, stream>>>(feats, sq, scalars);
        tile_fb<<<dim3(64, 64, 3), 256, 0, stream>>>(feats, sq, U, V);
        logred_kernel<<<N_HALF / 256, 256, 0, stream>>>(U, V, scalars);
        finalize_kernel<<<1, 1, 0, stream>>>(scalars, out);
    }
}

// Round 5
// 227.071 us; speedup vs baseline: 1.4480x; 1.0753x over previous
//
#include <hip/hip_runtime.h>

#define N_HALF 8192
#define D 128
#define TILE 128
#define CHUNK 8   // column tiles per band block

typedef __bf16 bf16x8 __attribute__((ext_vector_type(8)));
typedef float f32x4 __attribute__((ext_vector_type(4)));

// ws layout (4325392 B needed; same as R4):
// [0,       4194304)  bfF      (16384x128 bf16)  -- pre-converted features
// [4194304, 4259840)  sq       (16384 f32)
// [4259840, 4292608)  U        (8192 f32)   -- rowsum_aa + rowsum_ab
// [4292608, 4325376)  V        (8192 f32)   -- colsum_ab + rowsum_bb
// [4325376, 4325392)  scalars  (4 f32)      -- 0: align_sum
#define WS_NEED (4325392)

__device__ __forceinline__ unsigned short f2bf(float f) {
    unsigned int u = __float_as_uint(f);
    u += 0x7fffu + ((u >> 16) & 1u);   // round-to-nearest-even
    return (unsigned short)(u >> 16);
}

__device__ __forceinline__ void async_cp16(const unsigned short* g, unsigned short* l) {
    __builtin_amdgcn_global_load_lds(
        (const __attribute__((address_space(1))) void*)g,
        (__attribute__((address_space(3))) void*)l, 16, 0, 0);
}

// ---- prep: fp32 norms, diag alignment term, fp32->bf16 convert
__global__ __launch_bounds__(256) void prep_kernel(
    const float* __restrict__ feats, unsigned short* __restrict__ bfF,
    float* __restrict__ sq, float* __restrict__ scalars)
{
    const int wave = threadIdx.x >> 6, lane = threadIdx.x & 63;
    const int i = blockIdx.x * 4 + wave;   // i in [0, N_HALF)
    const float2* arow = (const float2*)(feats + (size_t)i * D);
    const float2* brow = (const float2*)(feats + (size_t)(i + N_HALF) * D);
    float2 av = arow[lane];
    float2 bv = brow[lane];
    unsigned int ua = ((unsigned int)f2bf(av.y) << 16) | f2bf(av.x);
    unsigned int ub = ((unsigned int)f2bf(bv.y) << 16) | f2bf(bv.x);
    ((unsigned int*)bfF)[(size_t)i * 64 + lane] = ua;
    ((unsigned int*)bfF)[(size_t)(i + N_HALF) * 64 + lane] = ub;

    float sa = av.x * av.x + av.y * av.y;
    float sb = bv.x * bv.x + bv.y * bv.y;
    float dt = av.x * bv.x + av.y * bv.y;
#pragma unroll
    for (int off = 32; off; off >>= 1) {
        sa += __shfl_xor(sa, off);
        sb += __shfl_xor(sb, off);
        dt += __shfl_xor(dt, off);
    }
    __shared__ float partial[4];
    if (lane == 0) {
        sq[i] = sa;
        sq[N_HALF + i] = sb;
        float d2 = fmaxf(sa + sb - 2.0f * dt, 0.0f);
        partial[wave] = -logf(d2 + 1.0f);   // log(sim_ab[i,i])
    }
    __syncthreads();
    if (threadIdx.x == 0)
        atomicAdd(&scalars[0], partial[0] + partial[1] + partial[2] + partial[3]);
}

// ---- persistent band kernel: block = (kind, row band ti, chunk of 8 column tiles)
// A fragments in registers (scaled by -2), B double-buffered via global_load_lds,
// row sums accumulated in registers across the band, col sums mirrored per tile.
__global__ __launch_bounds__(256, 2) void band_kernel(
    const unsigned short* __restrict__ bfF, const float* __restrict__ sq,
    float* __restrict__ U, float* __restrict__ V)
{
    __shared__ unsigned short lB[2][TILE * D];   // 2 x 32 KB double buffer

    const int kind = blockIdx.z;           // 0=ab, 1=aa, 2=bb
    const int ti = blockIdx.y;
    const int c0 = blockIdx.x * CHUNK;
    int tjs = c0, tje = c0 + CHUNK;
    if (kind != 0 && tjs < ti) tjs = ti;   // symmetric kinds: upper triangle
    if (tjs >= tje) return;

    const int i0 = ti * TILE;
    const int rowFeat = (kind == 2 ? N_HALF : 0) + i0;
    const int colBase = (kind == 1 ? 0 : N_HALF);
    float* rowDst = (kind == 2) ? V : U;
    float* colDst = (kind == 1) ? U : V;

    const int wave = threadIdx.x >> 6, lane = threadIdx.x & 63;
    const int l15 = lane & 15, quad = lane >> 4;
    const int sw = l15 & 7;
    const int wr = (wave >> 1) * 64;   // wave's 64x64 quadrant of the 128x128 tile
    const int wc = (wave & 1) * 64;

    // ---- A fragments: af[mi][kk], row = rowFeat+wr+mi*16+l15, k = kk*32+quad*8..+8
    // scaled by -2 exactly: per bf16  (x ^ 0x8000) + 0x0080  (sign flip, exp+1)
    bf16x8 af[4][4];
#pragma unroll
    for (int mi = 0; mi < 4; ++mi)
#pragma unroll
        for (int kk = 0; kk < 4; ++kk) {
            const size_t off = (size_t)(rowFeat + wr + mi * 16 + l15) * D + kk * 32 + quad * 8;
            union { uint4 u; bf16x8 v; } c;
            c.u = *(const uint4*)(bfF + off);
            c.u.x = (c.u.x ^ 0x80008000u) + 0x00800080u;
            c.u.y = (c.u.y ^ 0x80008000u) + 0x00800080u;
            c.u.z = (c.u.z ^ 0x80008000u) + 0x00800080u;
            c.u.w = (c.u.w ^ 0x80008000u) + 0x00800080u;
            af[mi][kk] = c.v;
        }

    // rs1[mi*4+r] = |a_row|^2 + 1  (row = wr+mi*16+quad*4+r)
    float rs1[16];
#pragma unroll
    for (int mi = 0; mi < 4; ++mi)
#pragma unroll
        for (int r = 0; r < 4; ++r)
            rs1[mi * 4 + r] = sq[rowFeat + wr + mi * 16 + quad * 4 + r] + 1.0f;

    float rowAcc[16];
#pragma unroll
    for (int x = 0; x < 16; ++x) rowAcc[x] = 0.f;

    // B staging: wave covers rows [wave*32, wave*32+32); lane (quad,l15) fills
    // physical chunk l15 of row (.. + k*4 + quad) with logical chunk l15^(row&7).
    auto stageB = [&](int tj, int s) {
        const unsigned short* Bb = bfF + (size_t)(colBase + tj * TILE) * D;
#pragma unroll
        for (int k = 0; k < 8; ++k) {
            const int r = wave * 32 + k * 4 + quad;
            const int c = l15 ^ (r & 7);
            async_cp16(Bb + r * D + c * 8, &lB[s][(wave * 32 + k * 4) * D]);
        }
    };

    stageB(tjs, 0);
    float csqN[4];
#pragma unroll
    for (int ni = 0; ni < 4; ++ni)
        csqN[ni] = sq[colBase + tjs * TILE + wc + ni * 16 + l15];

    float savedCol[4];
    int savedJ0 = -1;

    for (int t = tjs; t < tje; ++t) {
        const int s = (t - tjs) & 1;
        float csq[4] = {csqN[0], csqN[1], csqN[2], csqN[3]};
        __syncthreads();   // B(t) ready; prev reads of other buffer done

        if (t + 1 < tje) {
            stageB(t + 1, s ^ 1);   // prefetch next tile (drained at NEXT barrier)
#pragma unroll
            for (int ni = 0; ni < 4; ++ni)
                csqN[ni] = sq[colBase + (t + 1) * TILE + wc + ni * 16 + l15];
        }
        // deferred col-sum flush from previous tile (latency hides under compute)
        if (savedJ0 >= 0) {
#pragma unroll
            for (int ni = 0; ni < 4; ++ni) {
                float cv = savedCol[ni];
                cv += __shfl_xor(cv, 16);
                cv += __shfl_xor(cv, 32);
                if (quad == 0) atomicAdd(&colDst[savedJ0 + wc + ni * 16 + l15], cv);
            }
        }

        // acc init = |a_r|^2 + |b_c|^2 + 1; MFMA adds -2*dot  =>  acc = d2+1
        f32x4 acc[4][4];
#pragma unroll
        for (int mi = 0; mi < 4; ++mi)
#pragma unroll
            for (int ni = 0; ni < 4; ++ni)
#pragma unroll
                for (int r = 0; r < 4; ++r)
                    acc[mi][ni][r] = rs1[mi * 4 + r] + csq[ni];

#pragma unroll
        for (int kk = 0; kk < 4; ++kk) {
            const int pc = ((4 * kk + quad) ^ sw) * 8;
            bf16x8 bfr[4];
#pragma unroll
            for (int ni = 0; ni < 4; ++ni)
                bfr[ni] = *(const bf16x8*)&lB[s][(wc + ni * 16 + l15) * D + pc];
#pragma unroll
            for (int mi = 0; mi < 4; ++mi)
#pragma unroll
                for (int ni = 0; ni < 4; ++ni)
                    acc[mi][ni] = __builtin_amdgcn_mfma_f32_16x16x32_bf16(
                        af[mi][kk], bfr[ni], acc[mi][ni], 0, 0, 0);
        }

        // epilogue: sim = 1/max(acc,1); accumulate rows in regs, cols per tile
        const bool diag = (kind != 0) && (t == ti);
        float colPart[4] = {0.f, 0.f, 0.f, 0.f};
#pragma unroll
        for (int mi = 0; mi < 4; ++mi)
#pragma unroll
            for (int ni = 0; ni < 4; ++ni)
#pragma unroll
                for (int r = 0; r < 4; ++r) {
                    float sim = __builtin_amdgcn_rcpf(fmaxf(acc[mi][ni][r], 1.0f));
                    if (diag && (wr + mi * 16 + quad * 4 + r) == (wc + ni * 16 + l15))
                        sim = 0.0f;   // eye mask on aa/bb diagonal tiles
                    rowAcc[mi * 4 + r] += sim;
                    colPart[ni] += sim;
                }
        if (!diag) {
#pragma unroll
            for (int ni = 0; ni < 4; ++ni) savedCol[ni] = colPart[ni];
            savedJ0 = t * TILE;
        } else {
            savedJ0 = -1;   // diagonal tile covers both triangles; no mirror
        }
    }
    // final col flush
    if (savedJ0 >= 0) {
#pragma unroll
        for (int ni = 0; ni < 4; ++ni) {
            float cv = savedCol[ni];
            cv += __shfl_xor(cv, 16);
            cv += __shfl_xor(cv, 32);
            if (quad == 0) atomicAdd(&colDst[savedJ0 + wc + ni * 16 + l15], cv);
        }
    }
    // row sums: reduce over the 16 l15 lanes (cols), one atomic per row
#pragma unroll
    for (int x = 0; x < 16; ++x) {
        float v = rowAcc[x];
        v += __shfl_xor(v, 1);
        v += __shfl_xor(v, 2);
        v += __shfl_xor(v, 4);
        v += __shfl_xor(v, 8);
        if (l15 == 0)
            atomicAdd(&rowDst[i0 + wr + (x >> 2) * 16 + quad * 4 + (x & 3)], v);
    }
}

// ---- tail: sum of logs over U and V + finalize (single block)
__global__ __launch_bounds__(1024) void tail_kernel(
    const float* __restrict__ U, const float* __restrict__ V,
    const float* __restrict__ scalars, unsigned int* __restrict__ out)
{
    const int tid = threadIdx.x;
    float s = 0.f;
    for (int i = tid; i < N_HALF; i += 1024)
        s += logf(U[i]) + logf(V[i]);
#pragma unroll
    for (int off = 32; off; off >>= 1) s += __shfl_xor(s, off);
    __shared__ float ps[16];
    if ((tid & 63) == 0) ps[tid >> 6] = s;
    __syncthreads();
    if (tid == 0) {
        float tot = 0.f;
#pragma unroll
        for (int w = 0; w < 16; ++w) tot += ps[w];
        float loss = -((scalars[0] - 0.5f * tot) / (float)N_HALF);
        unsigned int h = (unsigned int)f2bf(loss);
        out[0] = (h << 16) | h;   // fp32 reader: loss @ bf16 precision; bf16 reader: h
    }
}

extern "C" void kernel_launch(void* const* d_in, const int* in_sizes, int n_in,
                              void* d_out, int out_size, void* d_ws, size_t ws_size,
                              hipStream_t stream)
{
    const float* feats = (const float*)d_in[0];
    unsigned int* out = (unsigned int*)d_out;
    char* ws = (char*)d_ws;
    unsigned short* bfF = (unsigned short*)(ws);
    float* sq      = (float*)(ws + 4194304);
    float* U       = (float*)(ws + 4259840);
    float* V       = (float*)(ws + 4292608);
    float* scalars = (float*)(ws + 4325376);

    hipMemsetAsync(U, 0, 65552, stream);   // U, V, scalars contiguous
    prep_kernel<<<N_HALF / 4, 256, 0, stream>>>(feats, bfF, sq, scalars);
    band_kernel<<<dim3(64 / CHUNK, 64, 3), 256, 0, stream>>>(bfF, sq, U, V);
    tail_kernel<<<1, 1024, 0, stream>>>(U, V, scalars, out);
}

// Round 6
// 208.491 us; speedup vs baseline: 1.5770x; 1.0891x over previous
//
#include <hip/hip_runtime.h>

#define N_HALF 8192
#define D 128

typedef __bf16 bf16x8 __attribute__((ext_vector_type(8)));
typedef float f32x4 __attribute__((ext_vector_type(4)));

// ws layout (4325392 B, same footprint as R4/R5):
// [0,       4194304)  bfF      (16384x128 bf16)  -- pre-converted features
// [4194304, 4259840)  sq       (16384 f32)       -- exact fp32 |row|^2
// [4259840, 4292608)  U        (8192 f32)        -- rowsum_aa + rowsum_ab
// [4292608, 4325376)  V        (8192 f32)        -- colsum_ab + rowsum_bb
// [4325376, 4325392)  scalars  (4 f32)           -- 0: align_sum
#define OFF_SQ 4194304
#define OFF_U  4259840
#define OFF_V  4292608
#define OFF_SC 4325376

__device__ __forceinline__ unsigned short f2bf(float f) {
    unsigned int u = __float_as_uint(f);
    u += 0x7fffu + ((u >> 16) & 1u);   // round-to-nearest-even
    return (unsigned short)(u >> 16);
}

// ---- prep: fp32 norms, exact diag alignment term, bf16 convert, U/V zero-init
__global__ __launch_bounds__(256) void prep_kernel(
    const float* __restrict__ feats, unsigned short* __restrict__ bfF,
    float* __restrict__ sq, float* __restrict__ U, float* __restrict__ V,
    float* __restrict__ scalars)
{
    const int wave = threadIdx.x >> 6, lane = threadIdx.x & 63;
    const int i = blockIdx.x * 4 + wave;   // i in [0, N_HALF)
    const float2* arow = (const float2*)(feats + (size_t)i * D);
    const float2* brow = (const float2*)(feats + (size_t)(i + N_HALF) * D);
    float2 av = arow[lane];
    float2 bv = brow[lane];
    unsigned int ua = ((unsigned int)f2bf(av.y) << 16) | f2bf(av.x);
    unsigned int ub = ((unsigned int)f2bf(bv.y) << 16) | f2bf(bv.x);
    ((unsigned int*)bfF)[(size_t)i * 64 + lane] = ua;
    ((unsigned int*)bfF)[(size_t)(i + N_HALF) * 64 + lane] = ub;

    // zero U/V slices (removes the big memset dispatch)
    if (threadIdx.x < 4)       U[blockIdx.x * 4 + threadIdx.x] = 0.f;
    else if (threadIdx.x < 8)  V[blockIdx.x * 4 + threadIdx.x - 4] = 0.f;

    float sa = av.x * av.x + av.y * av.y;
    float sb = bv.x * bv.x + bv.y * bv.y;
    float dt = av.x * bv.x + av.y * bv.y;
#pragma unroll
    for (int off = 32; off; off >>= 1) {
        sa += __shfl_xor(sa, off);
        sb += __shfl_xor(sb, off);
        dt += __shfl_xor(dt, off);
    }
    __shared__ float partial[4];
    if (lane == 0) {
        sq[i] = sa;
        sq[N_HALF + i] = sb;
        float d2 = fmaxf(sa + sb - 2.0f * dt, 0.0f);
        partial[wave] = -logf(d2 + 1.0f);   // log(sim_ab[i,i])
    }
    __syncthreads();
    if (threadIdx.x == 0)
        atomicAdd(&scalars[0], partial[0] + partial[1] + partial[2] + partial[3]);
}

// ---- wave-autonomous strip kernel: NO LDS, NO barriers.
// Each wave owns a 64-row strip (A frags in regs, scaled -2) and walks up to 8
// 64-col tiles, loading B fragments global->VGPR (L2-resident) one kk ahead.
// grid (16 chunks, 32 strip-quads, 3 kinds); block 256 = 4 independent waves.
__global__ __launch_bounds__(256, 2) void strip_kernel(
    const unsigned short* __restrict__ bfF, const float* __restrict__ sq,
    float* __restrict__ U, float* __restrict__ V)
{
    const int kind = blockIdx.z;           // 0=ab, 1=aa, 2=bb
    const int wave = threadIdx.x >> 6, lane = threadIdx.x & 63;
    const int strip = blockIdx.y * 4 + wave;   // 0..127 (64-row strips)
    int js = blockIdx.x * 8, je = js + 8;      // 64-col tile range
    if (kind != 0 && js < strip) js = strip;   // symmetric kinds: upper triangle
    if (js >= je) return;

    const int l15 = lane & 15, quad = lane >> 4;
    const int rowFeat = (kind == 2 ? N_HALF : 0) + strip * 64;
    const int colBase = (kind == 1 ? 0 : N_HALF);
    float* const rowDst = (kind == 2) ? V : U;
    float* const colDst = (kind == 1) ? U : V;   // mirror for symmetric kinds

    // A fragments af[mi][kk] (rows mi*16+l15, k = kk*32+quad*8), scaled by -2
    // exactly via bf16 bit trick: (x ^ 0x8000) + 0x0080 (sign flip, exp+1).
    bf16x8 af[4][4];
#pragma unroll
    for (int mi = 0; mi < 4; ++mi)
#pragma unroll
        for (int kk = 0; kk < 4; ++kk) {
            union { uint4 u; bf16x8 v; } c;
            c.u = *(const uint4*)(bfF + (size_t)(rowFeat + mi * 16 + l15) * D + kk * 32 + quad * 8);
            c.u.x = (c.u.x ^ 0x80008000u) + 0x00800080u;
            c.u.y = (c.u.y ^ 0x80008000u) + 0x00800080u;
            c.u.z = (c.u.z ^ 0x80008000u) + 0x00800080u;
            c.u.w = (c.u.w ^ 0x80008000u) + 0x00800080u;
            af[mi][kk] = c.v;
        }

    // rs1[mi*4+r] = |a_row|^2 + 1  (C/D row = quad*4+r within 16-block, m89)
    float rs1[16];
#pragma unroll
    for (int mi = 0; mi < 4; ++mi)
#pragma unroll
        for (int r = 0; r < 4; ++r)
            rs1[mi * 4 + r] = sq[rowFeat + mi * 16 + quad * 4 + r] + 1.0f;

    float rowAcc[16];
#pragma unroll
    for (int x = 0; x < 16; ++x) rowAcc[x] = 0.f;

    // B double buffer in registers; loadB(j,kk)->buf
    bf16x8 bb[2][4];
    auto loadB = [&](int j, int kk, int buf) {
        const unsigned short* p = bfF + (size_t)(colBase + j * 64 + l15) * D + kk * 32 + quad * 8;
#pragma unroll
        for (int ni = 0; ni < 4; ++ni)
            bb[buf][ni] = *(const bf16x8*)(p + ni * 16 * D);
    };

    float csqN[4];
#pragma unroll
    for (int ni = 0; ni < 4; ++ni)
        csqN[ni] = sq[colBase + js * 64 + ni * 16 + l15];
    loadB(js, 0, 0);

    float savedCol[4];
    int savedJ = -1;

    for (int j = js; j < je; ++j) {
        const bool diag = (kind != 0) && (j == strip);
        const int jn = (j + 1 < je) ? j + 1 : j;   // clamped next (redundant last load ok)
        float csq[4] = {csqN[0], csqN[1], csqN[2], csqN[3]};
#pragma unroll
        for (int ni = 0; ni < 4; ++ni)
            csqN[ni] = sq[colBase + jn * 64 + ni * 16 + l15];

        // deferred col-sum flush from previous tile (overlaps in-flight B loads)
        if (savedJ >= 0) {
#pragma unroll
            for (int ni = 0; ni < 4; ++ni) {
                float cv = savedCol[ni];
                cv += __shfl_xor(cv, 16);
                cv += __shfl_xor(cv, 32);
                if (quad == 0) atomicAdd(&colDst[savedJ + ni * 16 + l15], cv);
            }
        }

        // acc init = |a_r|^2 + |b_c|^2 + 1; MFMA adds -2*dot  =>  acc = d2+1
        f32x4 acc[4][4];
#pragma unroll
        for (int mi = 0; mi < 4; ++mi)
#pragma unroll
            for (int ni = 0; ni < 4; ++ni)
#pragma unroll
                for (int r = 0; r < 4; ++r)
                    acc[mi][ni][r] = rs1[mi * 4 + r] + csq[ni];

#pragma unroll
        for (int kk = 0; kk < 4; ++kk) {
            if (kk < 3) loadB(j, kk + 1, (kk + 1) & 1);   // prefetch next kk
            else        loadB(jn, 0, 0);                  // bridge into next tile
#pragma unroll
            for (int mi = 0; mi < 4; ++mi)
#pragma unroll
                for (int ni = 0; ni < 4; ++ni)
                    acc[mi][ni] = __builtin_amdgcn_mfma_f32_16x16x32_bf16(
                        af[mi][kk], bb[kk & 1][ni], acc[mi][ni], 0, 0, 0);
        }

        // epilogue: sim = 1/max(acc,1); rows accumulate in regs across the strip
        float colPart[4] = {0.f, 0.f, 0.f, 0.f};
#pragma unroll
        for (int mi = 0; mi < 4; ++mi)
#pragma unroll
            for (int ni = 0; ni < 4; ++ni)
#pragma unroll
                for (int r = 0; r < 4; ++r) {
                    float sim = __builtin_amdgcn_rcpf(fmaxf(acc[mi][ni][r], 1.0f));
                    if (diag && (mi * 16 + quad * 4 + r) == (ni * 16 + l15))
                        sim = 0.0f;   // eye mask on aa/bb diagonal tiles
                    rowAcc[mi * 4 + r] += sim;
                    colPart[ni] += sim;
                }
        if (!diag) {
#pragma unroll
            for (int ni = 0; ni < 4; ++ni) savedCol[ni] = colPart[ni];
            savedJ = j * 64;
        } else {
            savedJ = -1;   // diag tile covers both triangles; no mirror
        }
    }
    if (savedJ >= 0) {
#pragma unroll
        for (int ni = 0; ni < 4; ++ni) {
            float cv = savedCol[ni];
            cv += __shfl_xor(cv, 16);
            cv += __shfl_xor(cv, 32);
            if (quad == 0) atomicAdd(&colDst[savedJ + ni * 16 + l15], cv);
        }
    }
    // row sums: reduce over the 16 l15 lanes, one atomic per row, once per strip
#pragma unroll
    for (int x = 0; x < 16; ++x) {
        float v = rowAcc[x];
        v += __shfl_xor(v, 1);
        v += __shfl_xor(v, 2);
        v += __shfl_xor(v, 4);
        v += __shfl_xor(v, 8);
        if (l15 == 0)
            atomicAdd(&rowDst[strip * 64 + (x >> 2) * 16 + quad * 4 + (x & 3)], v);
    }
}

// ---- tail: sum of logs over U and V + finalize (single block)
__global__ __launch_bounds__(1024) void tail_kernel(
    const float* __restrict__ U, const float* __restrict__ V,
    const float* __restrict__ scalars, unsigned int* __restrict__ out)
{
    const int tid = threadIdx.x;
    float s = 0.f;
    for (int i = tid; i < N_HALF; i += 1024)
        s += logf(U[i]) + logf(V[i]);
#pragma unroll
    for (int off = 32; off; off >>= 1) s += __shfl_xor(s, off);
    __shared__ float ps[16];
    if ((tid & 63) == 0) ps[tid >> 6] = s;
    __syncthreads();
    if (tid == 0) {
        float tot = 0.f;
#pragma unroll
        for (int w = 0; w < 16; ++w) tot += ps[w];
        float loss = -((scalars[0] - 0.5f * tot) / (float)N_HALF);
        unsigned int h = (unsigned int)f2bf(loss);
        out[0] = (h << 16) | h;   // fp32 reader: loss @ bf16 precision; bf16 reader: h
    }
}

extern "C" void kernel_launch(void* const* d_in, const int* in_sizes, int n_in,
                              void* d_out, int out_size, void* d_ws, size_t ws_size,
                              hipStream_t stream)
{
    const float* feats = (const float*)d_in[0];
    unsigned int* out = (unsigned int*)d_out;
    char* ws = (char*)d_ws;
    unsigned short* bfF = (unsigned short*)(ws);
    float* sq      = (float*)(ws + OFF_SQ);
    float* U       = (float*)(ws + OFF_U);
    float* V       = (float*)(ws + OFF_V);
    float* scalars = (float*)(ws + OFF_SC);

    hipMemsetAsync(scalars, 0, 16, stream);   // only the align accumulator
    prep_kernel<<<N_HALF / 4, 256, 0, stream>>>(feats, bfF, sq, U, V, scalars);
    strip_kernel<<<dim3(16, 32, 3), 256, 0, stream>>>(bfF, sq, U, V);
    tail_kernel<<<1, 1024, 0, stream>>>(U, V, scalars, out);
}

// Round 7
// 173.327 us; speedup vs baseline: 1.8970x; 1.2029x over previous
//
#include <hip/hip_runtime.h>

#define N_HALF 8192
#define D 128

typedef __bf16 bf16x8 __attribute__((ext_vector_type(8)));
typedef float f32x4 __attribute__((ext_vector_type(4)));

// ws layout (4333568 B):
// [0,       4194304)  bfF     (16384x128 bf16)  -- pre-converted features
// [4194304, 4259840)  sq      (16384 f32)       -- exact fp32 |row|^2
// [4259840, 4292608)  U       (8192 f32)        -- rowsum_aa + rowsum_ab
// [4292608, 4325376)  V       (8192 f32)        -- colsum_ab + rowsum_bb
// [4325376, 4333568)  alignP  (2048 f32)        -- per-prep-block align partials
#define OFF_SQ 4194304
#define OFF_U  4259840
#define OFF_V  4292608
#define OFF_AL 4325376

__device__ __forceinline__ unsigned short f2bf(float f) {
    unsigned int u = __float_as_uint(f);
    u += 0x7fffu + ((u >> 16) & 1u);   // round-to-nearest-even
    return (unsigned short)(u >> 16);
}

__device__ __forceinline__ void async_cp16(const unsigned short* g, unsigned short* l) {
    __builtin_amdgcn_global_load_lds(
        (const __attribute__((address_space(1))) void*)g,
        (__attribute__((address_space(3))) void*)l, 16, 0, 0);
}

// ---- prep: fp32 norms, align partials (no atomics/memset), bf16 convert, U/V zero
__global__ __launch_bounds__(256) void prep_kernel(
    const float* __restrict__ feats, unsigned short* __restrict__ bfF,
    float* __restrict__ sq, float* __restrict__ U, float* __restrict__ V,
    float* __restrict__ alignP)
{
    const int wave = threadIdx.x >> 6, lane = threadIdx.x & 63;
    const int i = blockIdx.x * 4 + wave;   // i in [0, N_HALF)
    const float2* arow = (const float2*)(feats + (size_t)i * D);
    const float2* brow = (const float2*)(feats + (size_t)(i + N_HALF) * D);
    float2 av = arow[lane];
    float2 bv = brow[lane];
    unsigned int ua = ((unsigned int)f2bf(av.y) << 16) | f2bf(av.x);
    unsigned int ub = ((unsigned int)f2bf(bv.y) << 16) | f2bf(bv.x);
    ((unsigned int*)bfF)[(size_t)i * 64 + lane] = ua;
    ((unsigned int*)bfF)[(size_t)(i + N_HALF) * 64 + lane] = ub;

    if (threadIdx.x < 4)       U[blockIdx.x * 4 + threadIdx.x] = 0.f;
    else if (threadIdx.x < 8)  V[blockIdx.x * 4 + threadIdx.x - 4] = 0.f;

    float sa = av.x * av.x + av.y * av.y;
    float sb = bv.x * bv.x + bv.y * bv.y;
    float dt = av.x * bv.x + av.y * bv.y;
#pragma unroll
    for (int off = 32; off; off >>= 1) {
        sa += __shfl_xor(sa, off);
        sb += __shfl_xor(sb, off);
        dt += __shfl_xor(dt, off);
    }
    __shared__ float partial[4];
    if (lane == 0) {
        sq[i] = sa;
        sq[N_HALF + i] = sb;
        float d2 = fmaxf(sa + sb - 2.0f * dt, 0.0f);
        partial[wave] = -__logf(d2 + 1.0f);   // log(sim_ab[i,i])
    }
    __syncthreads();
    if (threadIdx.x == 0)
        alignP[blockIdx.x] = partial[0] + partial[1] + partial[2] + partial[3];
}

// ---- seg_kernel: flat 1088-job list. Block = 128-row band x 16 col-tiles (64 wide).
// 4 waves x 32 rows; A in regs (scaled -2); B 16KB/step LDS double-buffer via
// global_load_lds with XOR-16 swizzle; one barrier/step; strict-upper + mirror for sym.
__global__ __launch_bounds__(256, 4) void seg_kernel(
    const unsigned short* __restrict__ bfF, const float* __restrict__ sq,
    float* __restrict__ U, float* __restrict__ V)
{
    __shared__ unsigned short lB[2][64 * D];   // 2 x 16 KB
    __shared__ float sqC[1024];                // col |.|^2 for the whole chunk

    int kind, band, js, je;
    {
        const int jb = blockIdx.x;
        if (jb < 512) {                        // ab: 64 bands x 8 chunks of 16
            kind = 0; band = jb >> 3; js = (jb & 7) * 16; je = js + 16;
        } else {                               // aa/bb: triangle chunking, 288 each
            int id2 = jb - 512;
            kind = (id2 < 288) ? 1 : 2;
            int t = (id2 < 288) ? id2 : id2 - 288;
            int g = 0;
            while (t >= 8 * (8 - g)) { t -= 8 * (8 - g); ++g; }   // <=7 iters
            const int cpb = 8 - g;             // chunks per band in this group
            int bo = 0;
            while (t >= cpb) { t -= cpb; ++bo; }                  // <=7 iters
            band = 8 * g + bo;
            js = 2 * band + 16 * t;
            je = js + 16; if (je > 128) je = 128;
        }
    }

    const int rowFeat = (kind == 2 ? N_HALF : 0) + band * 128;
    const int colFeat = (kind == 1 ? 0 : N_HALF);
    float* const rowDst = (kind == 2) ? V : U;
    float* const colDst = (kind == 1) ? U : V;
    const bool sym = (kind != 0);

    const int wave = threadIdx.x >> 6, lane = threadIdx.x & 63;
    const int l15 = lane & 15, quad = lane >> 4;
    const int wRow0 = band * 128 + wave * 32;   // local first row of this wave

    // A fragments (32 rows), scaled by -2 exactly: (x ^ 0x8000) + 0x0080 per bf16
    bf16x8 af[2][4];
#pragma unroll
    for (int mi = 0; mi < 2; ++mi)
#pragma unroll
        for (int kk = 0; kk < 4; ++kk) {
            union { uint4 u; bf16x8 v; } c;
            c.u = *(const uint4*)(bfF + (size_t)(rowFeat + wave * 32 + mi * 16 + l15) * D
                                  + kk * 32 + quad * 8);
            c.u.x = (c.u.x ^ 0x80008000u) + 0x00800080u;
            c.u.y = (c.u.y ^ 0x80008000u) + 0x00800080u;
            c.u.z = (c.u.z ^ 0x80008000u) + 0x00800080u;
            c.u.w = (c.u.w ^ 0x80008000u) + 0x00800080u;
            af[mi][kk] = c.v;
        }

    float rs1[8];
#pragma unroll
    for (int mi = 0; mi < 2; ++mi)
#pragma unroll
        for (int r = 0; r < 4; ++r)
            rs1[mi * 4 + r] = sq[rowFeat + wave * 32 + mi * 16 + quad * 4 + r] + 1.0f;

    float rowAcc[8];
#pragma unroll
    for (int x = 0; x < 8; ++x) rowAcc[x] = 0.f;

    // stage one 64x128 B tile (16 KB): wave covers 16 rows; 4 DMA instrs of 1KB.
    // phys 16B-chunk p of row r holds logical chunk p ^ (r & 15).
    auto stage = [&](int j, int s) {
        const unsigned short* Bb = bfF + (size_t)(colFeat + j * 64) * D;
        unsigned short* dst = &lB[s][wave * 16 * D];
#pragma unroll
        for (int k = 0; k < 4; ++k) {
            const int r = wave * 16 + k * 4 + quad;
            const int c = l15 ^ (r & 15);
            async_cp16(Bb + r * D + c * 8, dst + k * 4 * D);
        }
    };

    stage(js, 0);
    {   // stage col norms for the chunk (<=1024 floats)
        const int cnt = (je - js) * 16;
        if ((int)threadIdx.x < cnt)
            ((float4*)sqC)[threadIdx.x] =
                ((const float4*)(sq + colFeat + js * 64))[threadIdx.x];
    }

    for (int t = js; t < je; ++t) {
        const int s = (t - js) & 1;
        __syncthreads();                       // drains stage(t) (issued a full step ago)
        if (t + 1 < je) stage(t + 1, s ^ 1);

        if (sym && (t * 64 + 64) <= wRow0) continue;   // fully below diagonal
        const bool maskDiag = sym && (t * 64 < wRow0 + 32);

        float csq[4];
#pragma unroll
        for (int ni = 0; ni < 4; ++ni)
            csq[ni] = sqC[(t - js) * 64 + ni * 16 + l15];

        // acc init = |a|^2 + |b|^2 + 1; MFMA adds -2*dot => acc = d2 + 1
        f32x4 acc[2][4];
#pragma unroll
        for (int mi = 0; mi < 2; ++mi)
#pragma unroll
            for (int ni = 0; ni < 4; ++ni)
#pragma unroll
                for (int r = 0; r < 4; ++r)
                    acc[mi][ni][r] = rs1[mi * 4 + r] + csq[ni];

#pragma unroll
        for (int kk = 0; kk < 4; ++kk) {
            bf16x8 bfr[4];
#pragma unroll
            for (int ni = 0; ni < 4; ++ni)
                bfr[ni] = *(const bf16x8*)&lB[s][(ni * 16 + l15) * D
                                                + (((kk * 4 + quad) ^ l15) << 3)];
#pragma unroll
            for (int mi = 0; mi < 2; ++mi)
#pragma unroll
                for (int ni = 0; ni < 4; ++ni)
                    acc[mi][ni] = __builtin_amdgcn_mfma_f32_16x16x32_bf16(
                        af[mi][kk], bfr[ni], acc[mi][ni], 0, 0, 0);
        }

        float colPart[4] = {0.f, 0.f, 0.f, 0.f};
#pragma unroll
        for (int mi = 0; mi < 2; ++mi)
#pragma unroll
            for (int ni = 0; ni < 4; ++ni)
#pragma unroll
                for (int r = 0; r < 4; ++r) {
                    float sim = __builtin_amdgcn_rcpf(fmaxf(acc[mi][ni][r], 1.0f));
                    if (maskDiag &&
                        (t * 64 + ni * 16 + l15) <= (wRow0 + mi * 16 + quad * 4 + r))
                        sim = 0.0f;            // keep strict upper only
                    rowAcc[mi * 4 + r] += sim;
                    colPart[ni] += sim;
                }
#pragma unroll
        for (int ni = 0; ni < 4; ++ni) {
            float cv = colPart[ni];
            cv += __shfl_xor(cv, 16);
            cv += __shfl_xor(cv, 32);
            if (quad == 0) atomicAdd(&colDst[t * 64 + ni * 16 + l15], cv);
        }
    }

    // row flush: reduce over 16 l15 lanes, one atomic per row
#pragma unroll
    for (int x = 0; x < 8; ++x) {
        float v = rowAcc[x];
        v += __shfl_xor(v, 1);
        v += __shfl_xor(v, 2);
        v += __shfl_xor(v, 4);
        v += __shfl_xor(v, 8);
        if (l15 == 0)
            atomicAdd(&rowDst[wRow0 + (x >> 2) * 16 + quad * 4 + (x & 3)], v);
    }
}

// ---- tail: sum logs of U,V + align partials -> loss (single block)
__global__ __launch_bounds__(1024) void tail_kernel(
    const float* __restrict__ U, const float* __restrict__ V,
    const float* __restrict__ alignP, unsigned int* __restrict__ out)
{
    const int tid = threadIdx.x;
    float s = 0.f;
    const float4* U4 = (const float4*)U;
    const float4* V4 = (const float4*)V;
#pragma unroll
    for (int k = 0; k < 2; ++k) {
        float4 u = U4[tid * 2 + k];
        float4 v = V4[tid * 2 + k];
        s += __logf(u.x) + __logf(u.y) + __logf(u.z) + __logf(u.w);
        s += __logf(v.x) + __logf(v.y) + __logf(v.z) + __logf(v.w);
    }
    float a = 0.f;
    if (tid < 512) {
        float4 t4 = ((const float4*)alignP)[tid];
        a = t4.x + t4.y + t4.z + t4.w;
    }
    float m = a - 0.5f * s;
#pragma unroll
    for (int off = 32; off; off >>= 1) m += __shfl_xor(m, off);
    __shared__ float ps[16];
    if ((tid & 63) == 0) ps[tid >> 6] = m;
    __syncthreads();
    if (tid == 0) {
        float tot = 0.f;
#pragma unroll
        for (int w = 0; w < 16; ++w) tot += ps[w];
        float loss = -(tot / (float)N_HALF);
        unsigned int h = (unsigned int)f2bf(loss);
        out[0] = (h << 16) | h;   // fp32 reader: loss @ bf16 precision; bf16 reader: h
    }
}

extern "C" void kernel_launch(void* const* d_in, const int* in_sizes, int n_in,
                              void* d_out, int out_size, void* d_ws, size_t ws_size,
                              hipStream_t stream)
{
    const float* feats = (const float*)d_in[0];
    unsigned int* out = (unsigned int*)d_out;
    char* ws = (char*)d_ws;
    unsigned short* bfF = (unsigned short*)(ws);
    float* sq     = (float*)(ws + OFF_SQ);
    float* U      = (float*)(ws + OFF_U);
    float* V      = (float*)(ws + OFF_V);
    float* alignP = (float*)(ws + OFF_AL);

    prep_kernel<<<N_HALF / 4, 256, 0, stream>>>(feats, bfF, sq, U, V, alignP);
    seg_kernel<<<1088, 256, 0, stream>>>(bfF, sq, U, V);
    tail_kernel<<<1, 1024, 0, stream>>>(U, V, alignP, out);
}

// Round 8
// 148.713 us; speedup vs baseline: 2.2110x; 1.1655x over previous
//
#include <hip/hip_runtime.h>

#define N_HALF 8192
#define D 128

typedef __bf16 bf16x8 __attribute__((ext_vector_type(8)));
typedef float f32x4 __attribute__((ext_vector_type(4)));

// ws layout (4333568 B):
// [0,       4194304)  bfS     -- bf16 features in MFMA-fragment-major layout:
//                        frag(T,kk,ni): elem ((T*4+kk)*4+ni)*512 + (quad*16+l15)*8 + j
//                        holds row T*64+ni*16+l15, k = kk*32+quad*8+j
// [4194304, 4259840)  sq      (16384 f32)  -- exact fp32 |row|^2
// [4259840, 4292608)  U       (8192 f32)   -- rowsum_aa + rowsum_ab
// [4292608, 4325376)  V       (8192 f32)   -- colsum_ab + rowsum_bb
// [4325376, 4333568)  alignP  (2048 f32)   -- per-prep-block align partials
#define OFF_SQ 4194304
#define OFF_U  4259840
#define OFF_V  4292608
#define OFF_AL 4325376

__device__ __forceinline__ unsigned short f2bf(float f) {
    unsigned int u = __float_as_uint(f);
    u += 0x7fffu + ((u >> 16) & 1u);   // round-to-nearest-even
    return (unsigned short)(u >> 16);
}

// ---- prep: fp32 norms, align partials, U/V zero, bf16 convert into fragment layout
__global__ __launch_bounds__(256) void prep_kernel(
    const float* __restrict__ feats, unsigned short* __restrict__ bfS,
    float* __restrict__ sq, float* __restrict__ U, float* __restrict__ V,
    float* __restrict__ alignP)
{
    const int wave = threadIdx.x >> 6, lane = threadIdx.x & 63;
    const int i = blockIdx.x * 4 + wave;   // i in [0, N_HALF)
    const float2 av = ((const float2*)(feats + (size_t)i * D))[lane];
    const float2 bv = ((const float2*)(feats + (size_t)(i + N_HALF) * D))[lane];
    const unsigned int ua = ((unsigned int)f2bf(av.y) << 16) | f2bf(av.x);
    const unsigned int ub = ((unsigned int)f2bf(bv.y) << 16) | f2bf(bv.x);

    // lane holds k = 2*lane, 2*lane+1  ->  kk = lane>>4, quad = (lane>>2)&3, j2 = lane&3
    const int kk = lane >> 4, q = (lane >> 2) & 3, j2 = lane & 3;
    {
        const int T = i >> 6, ni = (i >> 4) & 3, l = i & 15;
        ((unsigned int*)bfS)[((size_t)((T * 4 + kk) * 4 + ni)) * 256 + (q * 16 + l) * 4 + j2] = ua;
        const int i2 = i + N_HALF;
        const int T2 = i2 >> 6, ni2 = (i2 >> 4) & 3, l2 = i2 & 15;
        ((unsigned int*)bfS)[((size_t)((T2 * 4 + kk) * 4 + ni2)) * 256 + (q * 16 + l2) * 4 + j2] = ub;
    }

    if (threadIdx.x < 4)       U[blockIdx.x * 4 + threadIdx.x] = 0.f;
    else if (threadIdx.x < 8)  V[blockIdx.x * 4 + threadIdx.x - 4] = 0.f;

    float sa = av.x * av.x + av.y * av.y;
    float sb = bv.x * bv.x + bv.y * bv.y;
    float dt = av.x * bv.x + av.y * bv.y;
#pragma unroll
    for (int off = 32; off; off >>= 1) {
        sa += __shfl_xor(sa, off);
        sb += __shfl_xor(sb, off);
        dt += __shfl_xor(dt, off);
    }
    __shared__ float partial[4];
    if (lane == 0) {
        sq[i] = sa;
        sq[N_HALF + i] = sb;
        float d2 = fmaxf(sa + sb - 2.0f * dt, 0.0f);
        partial[wave] = -__logf(d2 + 1.0f);   // log(sim_ab[i,i])
    }
    __syncthreads();
    if (threadIdx.x == 0)
        alignP[blockIdx.x] = partial[0] + partial[1] + partial[2] + partial[3];
}

// ---- wave-autonomous fragment kernel: NO LDS, NO barriers.
// Each wave owns a 64-row strip x up to 8 col-tiles(64). All A/B fragment loads
// are fully-coalesced 1KB reads from the fragment-major bfS (L2-resident).
// Jobs: ab 2048, aa 1088, bb 1088 (triangle-chunked) = 4224 = 1056 blocks x 4 waves.
__global__ __launch_bounds__(256, 2) void wave_kernel(
    const unsigned short* __restrict__ bfS, const float* __restrict__ sq,
    float* __restrict__ U, float* __restrict__ V)
{
    const int wave = threadIdx.x >> 6, lane = threadIdx.x & 63;
    const int l15 = lane & 15, quad = lane >> 4;

    int id = blockIdx.x * 4 + wave;   // 0..4223
    int kind, strip, js;
    if (id < 2048) {                  // ab: 128 strips x 16 chunks of 8 tiles
        kind = 0; strip = id >> 4; js = (id & 15) * 8;
    } else {                          // aa/bb: triangle chunks, 1088 each
        int t = id - 2048;
        kind = 1;
        if (t >= 1088) { t -= 1088; kind = 2; }
        int g = 0;
        while (t >= 8 * (16 - g)) { t -= 8 * (16 - g); ++g; }   // <=15 iters
        const int cpb = 16 - g;
        strip = 8 * g + t / cpb;
        js = (g + t % cpb) * 8;
    }
    const bool sym = (kind != 0);
    const int T_A = (kind == 2 ? 128 : 0) + strip;   // A-side 64-row tile index
    const int T_B0 = (kind == 1 ? 0 : 128);          // B-side tile base
    const int colSqB = (kind == 1 ? 0 : N_HALF);
    float* const rowDst = (kind == 2) ? V : U;
    float* const colDst = (kind == 1) ? U : V;

    // A fragments af[mi][kk], scaled by -2 exactly: (x ^ 0x8000) + 0x0080 per bf16
    bf16x8 af[4][4];
#pragma unroll
    for (int mi = 0; mi < 4; ++mi)
#pragma unroll
        for (int kk = 0; kk < 4; ++kk) {
            union { uint4 u; bf16x8 v; } c;
            c.u = *(const uint4*)(bfS + ((size_t)((T_A * 4 + kk) * 4 + mi)) * 512 + lane * 8);
            c.u.x = (c.u.x ^ 0x80008000u) + 0x00800080u;
            c.u.y = (c.u.y ^ 0x80008000u) + 0x00800080u;
            c.u.z = (c.u.z ^ 0x80008000u) + 0x00800080u;
            c.u.w = (c.u.w ^ 0x80008000u) + 0x00800080u;
            af[mi][kk] = c.v;
        }

    float rs1[16];
#pragma unroll
    for (int mi = 0; mi < 4; ++mi)
#pragma unroll
        for (int r = 0; r < 4; ++r)
            rs1[mi * 4 + r] = sq[T_A * 64 + mi * 16 + quad * 4 + r] + 1.0f;

    float rowAcc[16];
#pragma unroll
    for (int x = 0; x < 16; ++x) rowAcc[x] = 0.f;

    const int je = js + 8;
    int j0 = js;
    if (sym && j0 < strip) j0 = strip;   // skip sub-diagonal tiles in first chunk

    bf16x8 bb[2][4];
    auto loadB = [&](int j, int kk, int buf) {
        const unsigned short* p = bfS + ((size_t)((T_B0 + j) * 4 + kk)) * 2048 + lane * 8;
#pragma unroll
        for (int ni = 0; ni < 4; ++ni)
            bb[buf][ni] = *(const bf16x8*)(p + ni * 512);
    };
    loadB(j0, 0, 0);

    float savedCol[4];
    int savedJ = -1;

    for (int j = j0; j < je; ++j) {
        const int jn = (j + 1 < je) ? j + 1 : j;   // clamp (redundant last load ok)
        float csq[4];
#pragma unroll
        for (int ni = 0; ni < 4; ++ni)
            csq[ni] = sq[colSqB + j * 64 + ni * 16 + l15];

        // acc init = |a|^2 + |b|^2 + 1; MFMA adds -2*dot => acc = d2 + 1
        f32x4 acc[4][4];
#pragma unroll
        for (int mi = 0; mi < 4; ++mi)
#pragma unroll
            for (int ni = 0; ni < 4; ++ni)
#pragma unroll
                for (int r = 0; r < 4; ++r)
                    acc[mi][ni][r] = rs1[mi * 4 + r] + csq[ni];

#pragma unroll
        for (int kk = 0; kk < 4; ++kk) {
            if (kk < 3) loadB(j, kk + 1, (kk + 1) & 1);
            else        loadB(jn, 0, 0);
#pragma unroll
            for (int mi = 0; mi < 4; ++mi)
#pragma unroll
                for (int ni = 0; ni < 4; ++ni)
                    acc[mi][ni] = __builtin_amdgcn_mfma_f32_16x16x32_bf16(
                        af[mi][kk], bb[kk & 1][ni], acc[mi][ni], 0, 0, 0);
        }

        // flush PREVIOUS tile's col atomics now: they sit BEHIND this tile's loads
        // in the in-order vmcnt queue, so no load-wait ever waits on an atomic.
        if (savedJ >= 0) {
#pragma unroll
            for (int ni = 0; ni < 4; ++ni) {
                float cv = savedCol[ni];
                cv += __shfl_xor(cv, 16);
                cv += __shfl_xor(cv, 32);
                if (quad == 0) atomicAdd(&colDst[savedJ + ni * 16 + l15], cv);
            }
        }

        const bool diag = sym && (j == strip);
        float colPart[4] = {0.f, 0.f, 0.f, 0.f};
#pragma unroll
        for (int mi = 0; mi < 4; ++mi)
#pragma unroll
            for (int ni = 0; ni < 4; ++ni)
#pragma unroll
                for (int r = 0; r < 4; ++r) {
                    float sim = __builtin_amdgcn_rcpf(fmaxf(acc[mi][ni][r], 1.0f));
                    if (diag && (ni * 16 + l15) <= (mi * 16 + quad * 4 + r))
                        sim = 0.0f;   // strict upper only on diagonal tiles
                    rowAcc[mi * 4 + r] += sim;
                    colPart[ni] += sim;
                }
#pragma unroll
        for (int ni = 0; ni < 4; ++ni) savedCol[ni] = colPart[ni];
        savedJ = j * 64;
    }

    if (savedJ >= 0) {   // final col flush
#pragma unroll
        for (int ni = 0; ni < 4; ++ni) {
            float cv = savedCol[ni];
            cv += __shfl_xor(cv, 16);
            cv += __shfl_xor(cv, 32);
            if (quad == 0) atomicAdd(&colDst[savedJ + ni * 16 + l15], cv);
        }
    }
    // row flush: reduce over 16 l15 lanes, one atomic per row, once per job
#pragma unroll
    for (int x = 0; x < 16; ++x) {
        float v = rowAcc[x];
        v += __shfl_xor(v, 1);
        v += __shfl_xor(v, 2);
        v += __shfl_xor(v, 4);
        v += __shfl_xor(v, 8);
        if (l15 == 0)
            atomicAdd(&rowDst[strip * 64 + (x >> 2) * 16 + quad * 4 + (x & 3)], v);
    }
}

// ---- tail: sum logs of U,V + align partials -> loss (single block)
__global__ __launch_bounds__(1024) void tail_kernel(
    const float* __restrict__ U, const float* __restrict__ V,
    const float* __restrict__ alignP, unsigned int* __restrict__ out)
{
    const int tid = threadIdx.x;
    float s = 0.f;
    const float4* U4 = (const float4*)U;
    const float4* V4 = (const float4*)V;
#pragma unroll
    for (int k = 0; k < 2; ++k) {
        float4 u = U4[tid * 2 + k];
        float4 v = V4[tid * 2 + k];
        s += __logf(u.x) + __logf(u.y) + __logf(u.z) + __logf(u.w);
        s += __logf(v.x) + __logf(v.y) + __logf(v.z) + __logf(v.w);
    }
    float a = 0.f;
    if (tid < 512) {
        float4 t4 = ((const float4*)alignP)[tid];
        a = t4.x + t4.y + t4.z + t4.w;
    }
    float m = a - 0.5f * s;
#pragma unroll
    for (int off = 32; off; off >>= 1) m += __shfl_xor(m, off);
    __shared__ float ps[16];
    if ((tid & 63) == 0) ps[tid >> 6] = m;
    __syncthreads();
    if (tid == 0) {
        float tot = 0.f;
#pragma unroll
        for (int w = 0; w < 16; ++w) tot += ps[w];
        float loss = -(tot / (float)N_HALF);
        unsigned int h = (unsigned int)f2bf(loss);
        out[0] = (h << 16) | h;   // fp32 reader: loss @ bf16 precision; bf16 reader: h
    }
}

extern "C" void kernel_launch(void* const* d_in, const int* in_sizes, int n_in,
                              void* d_out, int out_size, void* d_ws, size_t ws_size,
                              hipStream_t stream)
{
    const float* feats = (const float*)d_in[0];
    unsigned int* out = (unsigned int*)d_out;
    char* ws = (char*)d_ws;
    unsigned short* bfS = (unsigned short*)(ws);
    float* sq     = (float*)(ws + OFF_SQ);
    float* U      = (float*)(ws + OFF_U);
    float* V      = (float*)(ws + OFF_V);
    float* alignP = (float*)(ws + OFF_AL);

    prep_kernel<<<N_HALF / 4, 256, 0, stream>>>(feats, bfS, sq, U, V, alignP);
    wave_kernel<<<1056, 256, 0, stream>>>(bfS, sq, U, V);
    tail_kernel<<<1, 1024, 0, stream>>>(U, V, alignP, out);
}

// Round 9
// 140.526 us; speedup vs baseline: 2.3398x; 1.0583x over previous
//
#include <hip/hip_runtime.h>

#define N_HALF 8192
#define D 128

typedef __bf16 bf16x8 __attribute__((ext_vector_type(8)));
typedef float f32x4 __attribute__((ext_vector_type(4)));

// ws layout (4327424 B):
// [0,       4194304)  bfS     -- bf16 features, MFMA-fragment-major:
//                        frag(T,kk,ni): elem ((T*4+kk)*4+ni)*512 + (quad*16+l15)*8 + j
//                        holds row T*64+ni*16+l15, k = kk*32+quad*8+j
// [4194304, 4259840)  sq      (16384 f32)  -- exact fp32 |row|^2
// [4259840, 4292608)  U       (8192 f32)   -- rowsum_aa + rowsum_ab
// [4292608, 4325376)  V       (8192 f32)   -- colsum_ab + rowsum_bb
// [4325376, 4327424)  alignP  (512 f32)    -- per-prep-block align partials
#define OFF_SQ 4194304
#define OFF_U  4259840
#define OFF_V  4292608
#define OFF_AL 4325376

__device__ __forceinline__ unsigned short f2bf(float f) {
    unsigned int u = __float_as_uint(f);
    u += 0x7fffu + ((u >> 16) & 1u);   // round-to-nearest-even
    return (unsigned short)(u >> 16);
}

// ---- prep: block-local, fully-coalesced fragment emission.
// Block b owns a-rows 16b..16b+15 and b-rows +8192: stages them in LDS (fp32),
// computes norms + diag-align exactly, emits 8 complete 1KB fragments with
// 256B/wave contiguous stores (no partial-line scatter).
__global__ __launch_bounds__(256) void prep_kernel(
    const float* __restrict__ feats, unsigned short* __restrict__ bfS,
    float* __restrict__ sq, float* __restrict__ U, float* __restrict__ V,
    float* __restrict__ alignP)
{
    __shared__ float ld[32 * 132];   // 32 rows, stride 132 (bank skew)
    __shared__ float nrm[32];
    __shared__ float alg[16];

    const int b = blockIdx.x;        // 0..511
    const int t = threadIdx.x;
    const int A0 = b * 16;

    // stage 32 rows coalesced (float4)
#pragma unroll
    for (int it = 0; it < 4; ++it) {
        int idx = it * 256 + t;      // 0..1023
        int row = idx >> 5;          // 0..31
        int c4 = idx & 31;
        int grow = (row < 16) ? (A0 + row) : (N_HALF + A0 + row - 16);
        *(float4*)&ld[row * 132 + c4 * 4] =
            *(const float4*)(feats + (size_t)grow * D + c4 * 4);
    }
    if (t < 16)       U[A0 + t] = 0.f;
    else if (t < 32)  V[A0 + t - 16] = 0.f;
    __syncthreads();

    const int wave = t >> 6, lane = t & 63;
    // norms: wave w -> rows 8w..8w+7, 8 lanes per row
    {
        int r = 8 * wave + (lane >> 3);
        int k0 = (lane & 7) * 16;
        float s = 0.f;
#pragma unroll
        for (int k = 0; k < 16; k += 4) {
            float4 v = *(const float4*)&ld[r * 132 + k0 + k];
            s += v.x * v.x + v.y * v.y + v.z * v.z + v.w * v.w;
        }
        s += __shfl_xor(s, 1);
        s += __shfl_xor(s, 2);
        s += __shfl_xor(s, 4);
        if ((lane & 7) == 0) {
            nrm[r] = s;
            int grow = (r < 16) ? (A0 + r) : (N_HALF + A0 + r - 16);
            sq[grow] = s;
        }
    }
    __syncthreads();
    // diag alignment term: waves 0,1 pair row r with r+16 (a_i vs b_i)
    if (wave < 2) {
        int r = 8 * wave + (lane >> 3);
        int k0 = (lane & 7) * 16;
        float s = 0.f;
#pragma unroll
        for (int k = 0; k < 16; k += 4) {
            float4 a = *(const float4*)&ld[r * 132 + k0 + k];
            float4 bb = *(const float4*)&ld[(r + 16) * 132 + k0 + k];
            s += a.x * bb.x + a.y * bb.y + a.z * bb.z + a.w * bb.w;
        }
        s += __shfl_xor(s, 1);
        s += __shfl_xor(s, 2);
        s += __shfl_xor(s, 4);
        if ((lane & 7) == 0) {
            float d2 = fmaxf(nrm[r] + nrm[r + 16] - 2.0f * s, 0.0f);
            alg[r] = -__logf(d2 + 1.0f);
        }
    }
    // fragment emission: 16 rows = one (T,ni) for all kk -> 4 complete 1KB frags
    // per side; thread t writes dword t of each fragment (wave w = chunk-q w).
    const int l = (t >> 2) & 15, j2 = t & 3, q = t >> 6;
    const int Ta = b >> 2, ni = b & 3;
#pragma unroll
    for (int kk = 0; kk < 4; ++kk) {
        float2 va = *(const float2*)&ld[l * 132 + kk * 32 + q * 8 + j2 * 2];
        float2 vb = *(const float2*)&ld[(l + 16) * 132 + kk * 32 + q * 8 + j2 * 2];
        unsigned int ua = ((unsigned int)f2bf(va.y) << 16) | f2bf(va.x);
        unsigned int ub = ((unsigned int)f2bf(vb.y) << 16) | f2bf(vb.x);
        ((unsigned int*)bfS)[((size_t)((Ta * 4 + kk) * 4 + ni)) * 256 + t] = ua;
        ((unsigned int*)bfS)[((size_t)(((128 + Ta) * 4 + kk) * 4 + ni)) * 256 + t] = ub;
    }
    __syncthreads();
    if (t == 0) {
        float s = 0.f;
#pragma unroll
        for (int r = 0; r < 16; ++r) s += alg[r];
        alignP[b] = s;
    }
}

// ---- wave-autonomous fragment kernel, js-major job order for L1/L2 B-sharing.
// Jobs: ab 2048 (c-major), aa 1088, bb 1088 (column-chunk-major triangle).
// A block's 4 waves = consecutive strips, SAME column window -> shared B stream.
// B pipeline: 4 register buffers, slice kk+2 loaded while MFMA on kk (depth 2).
__global__ __launch_bounds__(256, 2) void wave_kernel(
    const unsigned short* __restrict__ bfS, const float* __restrict__ sq,
    float* __restrict__ U, float* __restrict__ V)
{
    const int wave = threadIdx.x >> 6, lane = threadIdx.x & 63;
    const int l15 = lane & 15, quad = lane >> 4;

    int id = blockIdx.x * 4 + wave;   // 0..4223
    int kind, strip, js;
    if (id < 2048) {                  // ab: column-chunk c = id>>7, strip = id&127
        kind = 0; strip = id & 127; js = (id >> 7) * 8;
    } else {
        int t = id - 2048;
        kind = 1;
        if (t >= 1088) { t -= 1088; kind = 2; }
        int c = 0;
        while (t >= 8 * c + 8) { t -= 8 * c + 8; ++c; }   // <=15 iters
        strip = t; js = 8 * c;        // strips 0..8c+7 for column chunk c
    }
    const bool sym = (kind != 0);
    const int T_A = (kind == 2 ? 128 : 0) + strip;
    const int T_B0 = (kind == 1 ? 0 : 128);
    const int colSqB = (kind == 1 ? 0 : N_HALF);
    float* const rowDst = (kind == 2) ? V : U;
    float* const colDst = (kind == 1) ? U : V;

    // A fragments, scaled by -2 exactly: (x ^ 0x8000) + 0x0080 per bf16
    bf16x8 af[4][4];
#pragma unroll
    for (int mi = 0; mi < 4; ++mi)
#pragma unroll
        for (int kk = 0; kk < 4; ++kk) {
            union { uint4 u; bf16x8 v; } c;
            c.u = *(const uint4*)(bfS + ((size_t)((T_A * 4 + kk) * 4 + mi)) * 512 + lane * 8);
            c.u.x = (c.u.x ^ 0x80008000u) + 0x00800080u;
            c.u.y = (c.u.y ^ 0x80008000u) + 0x00800080u;
            c.u.z = (c.u.z ^ 0x80008000u) + 0x00800080u;
            c.u.w = (c.u.w ^ 0x80008000u) + 0x00800080u;
            af[mi][kk] = c.v;
        }

    float rs1[16];
#pragma unroll
    for (int mi = 0; mi < 4; ++mi)
#pragma unroll
        for (int r = 0; r < 4; ++r)
            rs1[mi * 4 + r] = sq[T_A * 64 + mi * 16 + quad * 4 + r] + 1.0f;

    float rowAcc[16];
#pragma unroll
    for (int x = 0; x < 16; ++x) rowAcc[x] = 0.f;

    const int je = js + 8;
    int j0 = js;
    if (sym && j0 < strip) j0 = strip;

    bf16x8 bb[4][4];   // 4-slice pipeline (depth 2)
    auto loadB = [&](int j, int kk, int buf) {
        const unsigned short* p = bfS + ((size_t)((T_B0 + j) * 4 + kk)) * 2048 + lane * 8;
#pragma unroll
        for (int ni = 0; ni < 4; ++ni)
            bb[buf][ni] = *(const bf16x8*)(p + ni * 512);
    };
    loadB(j0, 0, 0);
    loadB(j0, 1, 1);

    float csqN[4];
#pragma unroll
    for (int ni = 0; ni < 4; ++ni)
        csqN[ni] = sq[colSqB + j0 * 64 + ni * 16 + l15];

    float savedCol[4];
    int savedJ = -1;

    for (int j = j0; j < je; ++j) {
        const int jn = (j + 1 < je) ? j + 1 : j;
        float csq[4] = {csqN[0], csqN[1], csqN[2], csqN[3]};
#pragma unroll
        for (int ni = 0; ni < 4; ++ni)                 // prefetch next tile's csq
            csqN[ni] = sq[colSqB + jn * 64 + ni * 16 + l15];

        // acc init = |a|^2 + |b|^2 + 1; MFMA adds -2*dot => acc = d2 + 1
        f32x4 acc[4][4];
#pragma unroll
        for (int mi = 0; mi < 4; ++mi)
#pragma unroll
            for (int ni = 0; ni < 4; ++ni)
#pragma unroll
                for (int r = 0; r < 4; ++r)
                    acc[mi][ni][r] = rs1[mi * 4 + r] + csq[ni];

#pragma unroll
        for (int kk = 0; kk < 4; ++kk) {
            const int tj = (kk < 2) ? j : jn;          // slice kk+2 (wraps into jn)
            loadB(tj, (kk + 2) & 3, (kk + 2) & 3);
#pragma unroll
            for (int mi = 0; mi < 4; ++mi)
#pragma unroll
                for (int ni = 0; ni < 4; ++ni)
                    acc[mi][ni] = __builtin_amdgcn_mfma_f32_16x16x32_bf16(
                        af[mi][kk], bb[kk][ni], acc[mi][ni], 0, 0, 0);
        }

        // previous tile's col atomics: issued behind this tile's loads in the queue
        if (savedJ >= 0) {
#pragma unroll
            for (int ni = 0; ni < 4; ++ni) {
                float cv = savedCol[ni];
                cv += __shfl_xor(cv, 16);
                cv += __shfl_xor(cv, 32);
                if (quad == 0) atomicAdd(&colDst[savedJ + ni * 16 + l15], cv);
            }
        }

        const bool diag = sym && (j == strip);
        float colPart[4] = {0.f, 0.f, 0.f, 0.f};
#pragma unroll
        for (int mi = 0; mi < 4; ++mi)
#pragma unroll
            for (int ni = 0; ni < 4; ++ni)
#pragma unroll
                for (int r = 0; r < 4; ++r) {
                    float sim = __builtin_amdgcn_rcpf(fmaxf(acc[mi][ni][r], 1.0f));
                    if (diag && (ni * 16 + l15) <= (mi * 16 + quad * 4 + r))
                        sim = 0.0f;   // strict upper only on diagonal tiles
                    rowAcc[mi * 4 + r] += sim;
                    colPart[ni] += sim;
                }
#pragma unroll
        for (int ni = 0; ni < 4; ++ni) savedCol[ni] = colPart[ni];
        savedJ = j * 64;
    }

    if (savedJ >= 0) {
#pragma unroll
        for (int ni = 0; ni < 4; ++ni) {
            float cv = savedCol[ni];
            cv += __shfl_xor(cv, 16);
            cv += __shfl_xor(cv, 32);
            if (quad == 0) atomicAdd(&colDst[savedJ + ni * 16 + l15], cv);
        }
    }
#pragma unroll
    for (int x = 0; x < 16; ++x) {
        float v = rowAcc[x];
        v += __shfl_xor(v, 1);
        v += __shfl_xor(v, 2);
        v += __shfl_xor(v, 4);
        v += __shfl_xor(v, 8);
        if (l15 == 0)
            atomicAdd(&rowDst[strip * 64 + (x >> 2) * 16 + quad * 4 + (x & 3)], v);
    }
}

// ---- tail: sum logs of U,V + align partials -> loss (single block)
__global__ __launch_bounds__(1024) void tail_kernel(
    const float* __restrict__ U, const float* __restrict__ V,
    const float* __restrict__ alignP, unsigned int* __restrict__ out)
{
    const int tid = threadIdx.x;
    float s = 0.f;
    const float4* U4 = (const float4*)U;
    const float4* V4 = (const float4*)V;
#pragma unroll
    for (int k = 0; k < 2; ++k) {
        float4 u = U4[tid * 2 + k];
        float4 v = V4[tid * 2 + k];
        s += __logf(u.x) + __logf(u.y) + __logf(u.z) + __logf(u.w);
        s += __logf(v.x) + __logf(v.y) + __logf(v.z) + __logf(v.w);
    }
    float a = 0.f;
    if (tid < 128) {
        float4 t4 = ((const float4*)alignP)[tid];
        a = t4.x + t4.y + t4.z + t4.w;
    }
    float m = a - 0.5f * s;
#pragma unroll
    for (int off = 32; off; off >>= 1) m += __shfl_xor(m, off);
    __shared__ float ps[16];
    if ((tid & 63) == 0) ps[tid >> 6] = m;
    __syncthreads();
    if (tid == 0) {
        float tot = 0.f;
#pragma unroll
        for (int w = 0; w < 16; ++w) tot += ps[w];
        float loss = -(tot / (float)N_HALF);
        unsigned int h = (unsigned int)f2bf(loss);
        out[0] = (h << 16) | h;   // fp32 reader: loss @ bf16 precision; bf16 reader: h
    }
}

extern "C" void kernel_launch(void* const* d_in, const int* in_sizes, int n_in,
                              void* d_out, int out_size, void* d_ws, size_t ws_size,
                              hipStream_t stream)
{
    const float* feats = (const float*)d_in[0];
    unsigned int* out = (unsigned int*)d_out;
    char* ws = (char*)d_ws;
    unsigned short* bfS = (unsigned short*)(ws);
    float* sq     = (float*)(ws + OFF_SQ);
    float* U      = (float*)(ws + OFF_U);
    float* V      = (float*)(ws + OFF_V);
    float* alignP = (float*)(ws + OFF_AL);

    prep_kernel<<<512, 256, 0, stream>>>(feats, bfS, sq, U, V, alignP);
    wave_kernel<<<1056, 256, 0, stream>>>(bfS, sq, U, V);
    tail_kernel<<<1, 1024, 0, stream>>>(U, V, alignP, out);
}